// Round 2
// baseline (445.608 us; speedup 1.0000x reference)
//
#include <hip/hip_runtime.h>
#include <hip/hip_bf16.h>

#define M_TOTAL (32 * 64 * 64)   // B*H*W = 131072 rows
#define CDIM 256
#define HDIM 1024

typedef float  floatx4 __attribute__((ext_vector_type(4)));
typedef short  short8  __attribute__((ext_vector_type(8)));

// ---------------------------------------------------------------------------
// Kernel 1: fused  x_new = x + LN1(x)  (stored bf16)  and  ln2 = LN2(x_new) bf16
// One wave per row of 256 floats; 4 rows per 256-thread block.
// ---------------------------------------------------------------------------
__global__ __launch_bounds__(256) void ln_fused(
    const float* __restrict__ x,
    const float* __restrict__ g1, const float* __restrict__ b1,
    const float* __restrict__ g2, const float* __restrict__ b2,
    __hip_bfloat16* __restrict__ xnew, __hip_bfloat16* __restrict__ ln2o)
{
    const int  wave = threadIdx.x >> 6;
    const int  lane = threadIdx.x & 63;
    const long row  = (long)blockIdx.x * 4 + wave;

    const float4 v = ((const float4*)(x + row * CDIM))[lane];
    float s  = v.x + v.y + v.z + v.w;
    float sq = v.x * v.x + v.y * v.y + v.z * v.z + v.w * v.w;
#pragma unroll
    for (int o = 1; o < 64; o <<= 1) { s += __shfl_xor(s, o); sq += __shfl_xor(sq, o); }
    const float mu = s * (1.f / CDIM);
    const float rs = rsqrtf(sq * (1.f / CDIM) - mu * mu + 1e-5f);

    const float4 G1 = ((const float4*)g1)[lane];
    const float4 B1 = ((const float4*)b1)[lane];
    float4 xn;
    xn.x = v.x + (v.x - mu) * rs * G1.x + B1.x;
    xn.y = v.y + (v.y - mu) * rs * G1.y + B1.y;
    xn.z = v.z + (v.z - mu) * rs * G1.z + B1.z;
    xn.w = v.w + (v.w - mu) * rs * G1.w + B1.w;
    union { ushort4 u; __hip_bfloat16 h[4]; } ox;
    ox.h[0] = __float2bfloat16(xn.x); ox.h[1] = __float2bfloat16(xn.y);
    ox.h[2] = __float2bfloat16(xn.z); ox.h[3] = __float2bfloat16(xn.w);
    ((ushort4*)(xnew + row * CDIM))[lane] = ox.u;

    float s2 = xn.x + xn.y + xn.z + xn.w;
    float q2 = xn.x * xn.x + xn.y * xn.y + xn.z * xn.z + xn.w * xn.w;
#pragma unroll
    for (int o = 1; o < 64; o <<= 1) { s2 += __shfl_xor(s2, o); q2 += __shfl_xor(q2, o); }
    const float mu2 = s2 * (1.f / CDIM);
    const float rs2 = rsqrtf(q2 * (1.f / CDIM) - mu2 * mu2 + 1e-5f);

    const float4 G2 = ((const float4*)g2)[lane];
    const float4 B2 = ((const float4*)b2)[lane];
    union { ushort4 u; __hip_bfloat16 h[4]; } o4;
    o4.h[0] = __float2bfloat16((xn.x - mu2) * rs2 * G2.x + B2.x);
    o4.h[1] = __float2bfloat16((xn.y - mu2) * rs2 * G2.y + B2.y);
    o4.h[2] = __float2bfloat16((xn.z - mu2) * rs2 * G2.z + B2.z);
    o4.h[3] = __float2bfloat16((xn.w - mu2) * rs2 * G2.w + B2.w);
    ((ushort4*)(ln2o + row * CDIM))[lane] = o4.u;
}

// ---------------------------------------------------------------------------
// Kernel 2: transpose + fp32->bf16 convert.  src[R][Cc] f32 -> dst[Cc][R] bf16
// ---------------------------------------------------------------------------
__global__ __launch_bounds__(256) void transpose_cvt(
    const float* __restrict__ src, __hip_bfloat16* __restrict__ dst,
    int R, int Cc)
{
    const int idx = blockIdx.x * 256 + threadIdx.x;   // idx = c*R + r
    const int r = idx % R;
    const int c = idx / R;
    dst[idx] = __float2bfloat16(src[(long)r * Cc + c]);
}

// fast exact-ish GELU (tanh form), max dev vs erf-GELU ~1e-3
__device__ __forceinline__ float gelu_fast(float v)
{
    const float t = v * __builtin_fmaf(v * v, 0.044715f, 1.0f);
    const float e = __expf(t * -1.5957691216f);          // v_exp_f32 path
    return v * __builtin_amdgcn_rcpf(1.0f + e);
}

#define GLL(gp, lp)                                                           \
    __builtin_amdgcn_global_load_lds(                                         \
        (const __attribute__((address_space(1))) void*)(uintptr_t)(gp),       \
        (__attribute__((address_space(3))) void*)(unsigned)(uintptr_t)(lp),   \
        16, 0, 0)

// ---------------------------------------------------------------------------
// Kernel 3: bf16 MFMA GEMM, C = A[M][K] * Bt[N][K]^T, 128x128 tile, BK=32,
// 4 waves (2x2, 64x64 each). LDS layout = [slot][row] 16B chunks -> the
// quarter-wave fragment reads are 256B-contiguous (conflict-free).
// Wave w stages k-slot w (linear LDS dest, per-lane global row source).
// EPI==0: Cout = bf16 GELU(acc + bias)            (fc1 + GELU)
// EPI==1: Cout = f32  acc + bias + bf16 resid     (fc2 + residual)
// ---------------------------------------------------------------------------
template<int KTOT, int EPI, int LOG2_TN>
__global__ __launch_bounds__(256) void gemm_bt(
    const __hip_bfloat16* __restrict__ A,
    const __hip_bfloat16* __restrict__ Bt,
    const float* __restrict__ bias,
    const __hip_bfloat16* __restrict__ resid,
    void* __restrict__ Cout, int Ncols)
{
    __shared__ __align__(16) __hip_bfloat16 As[4096];  // 4 slots x 128 rows x 8
    __shared__ __align__(16) __hip_bfloat16 Bs[4096];

    const int tid  = threadIdx.x;
    const int wave = tid >> 6;
    const int lane = tid & 63;

    // bijective XCD-aware swizzle: 8 consecutive logical tiles -> same XCD
    const int nwg  = gridDim.x * gridDim.y;           // multiple of 8
    const int flat = blockIdx.x + gridDim.x * blockIdx.y;
    const int l    = (flat & 7) * (nwg >> 3) + (flat >> 3);
    const int tn   = l & ((1 << LOG2_TN) - 1);
    const int tm   = l >> LOG2_TN;
    const long m0  = (long)tm * 128;
    const int  n0  = tn * 128;

    const int wr = (wave >> 1) * 64;   // wave row offset in tile
    const int wc = (wave & 1) * 64;    // wave col offset in tile
    const int fr = lane & 15;
    const int fq = lane >> 4;

    // staging pointers: wave w loads k-slot w, rows p*64+lane
    const __hip_bfloat16* gA0 = A  + (m0 + lane) * (long)KTOT + wave * 8;
    const __hip_bfloat16* gA1 = gA0 + 64 * (long)KTOT;
    const __hip_bfloat16* gB0 = Bt + ((long)n0 + lane) * KTOT + wave * 8;
    const __hip_bfloat16* gB1 = gB0 + 64 * (long)KTOT;
    __hip_bfloat16* lA0 = As + wave * 1024;
    __hip_bfloat16* lA1 = lA0 + 512;
    __hip_bfloat16* lB0 = Bs + wave * 1024;
    __hip_bfloat16* lB1 = lB0 + 512;

    floatx4 acc[4][4] = {};

    for (int k0 = 0; k0 < KTOT; k0 += 32) {
        __syncthreads();               // prev iteration's LDS reads done
        GLL(gA0, lA0); GLL(gA1, lA1);
        GLL(gB0, lB0); GLL(gB1, lB1);
        gA0 += 32; gA1 += 32; gB0 += 32; gB1 += 32;
        __syncthreads();               // staged data visible

        short8 af[4], bf[4];
        const __hip_bfloat16* pa = As + fq * 1024 + (wr + fr) * 8;
        const __hip_bfloat16* pb = Bs + fq * 1024 + (wc + fr) * 8;
#pragma unroll
        for (int m = 0; m < 4; ++m) af[m] = *(const short8*)(pa + m * 128);
#pragma unroll
        for (int n = 0; n < 4; ++n) bf[n] = *(const short8*)(pb + n * 128);
#pragma unroll
        for (int m = 0; m < 4; ++m)
#pragma unroll
            for (int n = 0; n < 4; ++n)
                acc[m][n] = __builtin_amdgcn_mfma_f32_16x16x32_bf16(
                    af[m], bf[n], acc[m][n], 0, 0, 0);
    }

    // Epilogue.  C/D layout: col = lane&15, row = (lane>>4)*4 + reg
    float bb[4];
#pragma unroll
    for (int n = 0; n < 4; ++n) bb[n] = bias[n0 + wc + n * 16 + fr];

    if (EPI == 0) {
        __hip_bfloat16* Cb = (__hip_bfloat16*)Cout;
#pragma unroll
        for (int m = 0; m < 4; ++m) {
            const long rbase = m0 + wr + m * 16 + fq * 4;
#pragma unroll
            for (int n = 0; n < 4; ++n) {
                const int col = n0 + wc + n * 16 + fr;
#pragma unroll
                for (int j = 0; j < 4; ++j) {
                    const float v = acc[m][n][j] + bb[n];
                    Cb[(rbase + j) * Ncols + col] = __float2bfloat16(gelu_fast(v));
                }
            }
        }
    } else {
        float* Cf = (float*)Cout;
#pragma unroll
        for (int m = 0; m < 4; ++m) {
            const long rbase = m0 + wr + m * 16 + fq * 4;
#pragma unroll
            for (int n = 0; n < 4; ++n) {
                const int col = n0 + wc + n * 16 + fr;
#pragma unroll
                for (int j = 0; j < 4; ++j) {
                    const float r = __bfloat162float(resid[(rbase + j) * Ncols + col]);
                    Cf[(rbase + j) * Ncols + col] = acc[m][n][j] + bb[n] + r;
                }
            }
        }
    }
}

// ---------------------------------------------------------------------------
extern "C" void kernel_launch(void* const* d_in, const int* in_sizes, int n_in,
                              void* d_out, int out_size, void* d_ws, size_t ws_size,
                              hipStream_t stream)
{
    const float* x    = (const float*)d_in[0];
    const float* ln1g = (const float*)d_in[1];
    const float* ln1b = (const float*)d_in[2];
    const float* ln2g = (const float*)d_in[3];
    const float* ln2b = (const float*)d_in[4];
    const float* w1   = (const float*)d_in[5];
    const float* b1   = (const float*)d_in[6];
    const float* w2   = (const float*)d_in[7];
    const float* b2   = (const float*)d_in[8];
    float* out = (float*)d_out;

    // workspace layout (bytes)
    char* ws = (char*)d_ws;
    __hip_bfloat16* xnew = (__hip_bfloat16*)ws;                        //  67,108,864
    __hip_bfloat16* ln2o = (__hip_bfloat16*)(ws + 67108864);           //  67,108,864
    __hip_bfloat16* act  = (__hip_bfloat16*)(ws + 134217728);          // 268,435,456
    __hip_bfloat16* w1t  = (__hip_bfloat16*)(ws + 402653184);          //     524,288
    __hip_bfloat16* w2t  = (__hip_bfloat16*)(ws + 403177472);          //     524,288

    // 1) fused LN1-residual + LN2
    ln_fused<<<M_TOTAL / 4, 256, 0, stream>>>(x, ln1g, ln1b, ln2g, ln2b, xnew, ln2o);

    // 2) weight transpose + bf16 convert
    transpose_cvt<<<(CDIM * HDIM) / 256, 256, 0, stream>>>(w1, w1t, CDIM, HDIM); // w1t[1024][256]
    transpose_cvt<<<(CDIM * HDIM) / 256, 256, 0, stream>>>(w2, w2t, HDIM, CDIM); // w2t[256][1024]

    // 3) fc1 + GELU :  act[M][1024] = GELU(ln2o[M][256] @ w1 + b1)
    gemm_bt<CDIM, 0, 3><<<dim3(HDIM / 128, M_TOTAL / 128), 256, 0, stream>>>(
        ln2o, w1t, b1, nullptr, (void*)act, HDIM);

    // 4) fc2 + residual :  out[M][256] = act @ w2 + b2 + xnew
    gemm_bt<HDIM, 1, 1><<<dim3(CDIM / 128, M_TOTAL / 128), 256, 0, stream>>>(
        act, w2t, b2, xnew, (void*)out, CDIM);
}